// Round 1
// baseline (665.842 us; speedup 1.0000x reference)
//
#include <hip/hip_runtime.h>
#include <math.h>

typedef __bf16 bf16;
typedef bf16 bf16x4 __attribute__((ext_vector_type(4)));
typedef bf16 bf16x8 __attribute__((ext_vector_type(8)));
typedef float f32x4 __attribute__((ext_vector_type(4)));

#define T_TOK   1024
#define H_DIM   2048
#define I_DIM   1024
#define E_NUM   16
#define NPAIR_R 4096
#define NPAIR   5120
#define LDSS    40   // 32 + 8 pad: 80B row stride -> 2-way LDS conflicts only (free)

// ---------------- router ----------------
__global__ __launch_bounds__(256) void router_kernel(
    const float* __restrict__ x, const float* __restrict__ gate_w,
    const float* __restrict__ e_bias,
    int* __restrict__ topk_ids, float* __restrict__ topk_w,
    int* __restrict__ counts)
{
  int t = blockIdx.x;
  int tid = threadIdx.x;
  float acc[16];
#pragma unroll
  for (int e = 0; e < 16; ++e) acc[e] = 0.f;
  const float* xr = x + (size_t)t * H_DIM;
  for (int h = tid; h < H_DIM; h += 256) {
    float xv = xr[h];
#pragma unroll
    for (int e = 0; e < 16; ++e) acc[e] += xv * gate_w[e * H_DIM + h];
  }
#pragma unroll
  for (int e = 0; e < 16; ++e) {
#pragma unroll
    for (int off = 32; off >= 1; off >>= 1)
      acc[e] += __shfl_down(acc[e], off, 64);
  }
  __shared__ float red[4][16];
  int lane = tid & 63, wave = tid >> 6;
  if (lane == 0) {
#pragma unroll
    for (int e = 0; e < 16; ++e) red[wave][e] = acc[e];
  }
  __syncthreads();
  if (tid == 0) {
    float scores[16], sb[16];
    for (int e = 0; e < 16; ++e) {
      float l = red[0][e] + red[1][e] + red[2][e] + red[3][e];
      float s = 1.f / (1.f + expf(-l));
      scores[e] = s;
      sb[e] = s + e_bias[e];
    }
    // group scores: sum of top-2 biased scores in each group of 4
    float gs[4];
    for (int g = 0; g < 4; ++g) {
      float b1 = -1e30f, b2 = -1e30f;
      for (int j = 0; j < 4; ++j) {
        float v = sb[g * 4 + j];
        if (v > b1) { b2 = b1; b1 = v; }
        else if (v > b2) b2 = v;
      }
      gs[g] = b1 + b2;
    }
    // top-2 groups, ties -> lower index (strict >)
    int g1 = 0; float bv = gs[0];
    for (int g = 1; g < 4; ++g) if (gs[g] > bv) { bv = gs[g]; g1 = g; }
    int g2 = -1; float bv2 = -1e30f;
    for (int g = 0; g < 4; ++g) if (g != g1 && gs[g] > bv2) { bv2 = gs[g]; g2 = g; }
    // masked biased scores (exactly like jnp.where(mask, sb, 0.0))
    float tmp[16];
    for (int e = 0; e < 16; ++e) {
      int grp = e >> 2;
      tmp[e] = (grp == g1 || grp == g2) ? sb[e] : 0.0f;
    }
    // top-4 of tmp, stable (lower index wins ties)
    bool used[16] = {false};
    int ids[4]; float wv[4]; float wsum = 0.f;
    for (int k = 0; k < 4; ++k) {
      int bi = 0; float bvv = -1e30f;
      for (int i = 0; i < 16; ++i)
        if (!used[i] && tmp[i] > bvv) { bvv = tmp[i]; bi = i; }
      used[bi] = true;
      ids[k] = bi; wv[k] = scores[bi]; wsum += scores[bi];
    }
    float inv = 1.f / wsum;
    for (int k = 0; k < 4; ++k) {
      topk_ids[t * 4 + k] = ids[k];
      topk_w[t * 4 + k] = wv[k] * inv;
      atomicAdd(&counts[ids[k]], 1);
    }
  }
}

// ---------------- offsets (prefix sum over 16 counts) ----------------
__global__ void offsets_kernel(const int* __restrict__ counts, int* __restrict__ off)
{
  if (threadIdx.x == 0 && blockIdx.x == 0) {
    int s = 0;
    for (int e = 0; e < 16; ++e) { off[e] = s; s += counts[e]; }
    off[16] = s;  // == 4096
  }
}

// ---------------- scatter pairs ----------------
__global__ __launch_bounds__(256) void scatter_kernel(
    const int* __restrict__ topk_ids, const float* __restrict__ topk_w,
    const int* __restrict__ off, int* __restrict__ cursor,
    int* __restrict__ pair_token, float* __restrict__ pair_scale)
{
  int i = blockIdx.x * 256 + threadIdx.x;
  if (i < NPAIR_R) {
    int e = topk_ids[i];
    float w = topk_w[i];
    int pos = atomicAdd(&cursor[e], 1);
    int idx = off[e] + pos;
    pair_token[idx] = i >> 2;
    pair_scale[idx] = 2.5f * w;
  } else if (i < NPAIR) {
    pair_token[i] = i - NPAIR_R;  // shared expert: identity token list
    pair_scale[i] = 1.0f;
  }
}

// ---------------- gate_up GEMM: gu[p, n] = sum_k x[token[p],k] * W[n,k] ----------------
__global__ __launch_bounds__(256) void gateup_kernel(
    const float* __restrict__ x, const float* __restrict__ w_gu,
    const float* __restrict__ s_wgu,
    const int* __restrict__ off, const int* __restrict__ pair_token,
    bf16* __restrict__ gu_buf)
{
  const int nt = blockIdx.x;   // 0..15 over N=2I=2048
  const int mt = blockIdx.y;   // 0..7
  const int e  = blockIdx.z;   // 0..16 (16 = shared)
  const int poff = (e < 16) ? off[e]     : NPAIR_R;
  const int pend = (e < 16) ? off[e + 1] : NPAIR;
  const int cnt  = pend - poff;
  if (mt * 128 >= cnt) return;
  const float* __restrict__ B = (e < 16) ? (w_gu + (size_t)e * 2 * I_DIM * H_DIM) : s_wgu;

  __shared__ bf16 As[128 * LDSS];
  __shared__ bf16 Bs[128 * LDSS];

  const int tid = threadIdx.x;
  const int lane = tid & 63, wave = tid >> 6;
  const int wm = wave >> 1, wn = wave & 1;
  const int srow = tid >> 1;
  const int scol = (tid & 1) * 16;

  int rloc = mt * 128 + srow;
  int p_eff = poff + (rloc < cnt ? rloc : cnt - 1);
  const float* __restrict__ Arow = x + (size_t)pair_token[p_eff] * H_DIM;
  const float* __restrict__ Brow = B + (size_t)(nt * 128 + srow) * H_DIM;

  f32x4 acc[4][4];
  f32x4 zz = {0.f, 0.f, 0.f, 0.f};
#pragma unroll
  for (int mi = 0; mi < 4; ++mi)
#pragma unroll
    for (int ni = 0; ni < 4; ++ni) acc[mi][ni] = zz;

  for (int k0 = 0; k0 < H_DIM; k0 += 32) {
#pragma unroll
    for (int i = 0; i < 4; ++i) {
      float4 av = *(const float4*)(Arow + k0 + scol + 4 * i);
      float4 bv = *(const float4*)(Brow + k0 + scol + 4 * i);
      bf16x4 a4, b4;
      a4[0] = (bf16)av.x; a4[1] = (bf16)av.y; a4[2] = (bf16)av.z; a4[3] = (bf16)av.w;
      b4[0] = (bf16)bv.x; b4[1] = (bf16)bv.y; b4[2] = (bf16)bv.z; b4[3] = (bf16)bv.w;
      *(bf16x4*)(&As[srow * LDSS + scol + 4 * i]) = a4;
      *(bf16x4*)(&Bs[srow * LDSS + scol + 4 * i]) = b4;
    }
    __syncthreads();
    const int kq = (lane >> 4) * 8;
    bf16x8 af[4], bfv[4];
#pragma unroll
    for (int mi = 0; mi < 4; ++mi)
      af[mi] = *(const bf16x8*)(&As[(wm * 64 + mi * 16 + (lane & 15)) * LDSS + kq]);
#pragma unroll
    for (int ni = 0; ni < 4; ++ni)
      bfv[ni] = *(const bf16x8*)(&Bs[(wn * 64 + ni * 16 + (lane & 15)) * LDSS + kq]);
#pragma unroll
    for (int mi = 0; mi < 4; ++mi)
#pragma unroll
      for (int ni = 0; ni < 4; ++ni)
        acc[mi][ni] = __builtin_amdgcn_mfma_f32_16x16x32_bf16(af[mi], bfv[ni], acc[mi][ni], 0, 0, 0);
    __syncthreads();
  }

  const int colb = nt * 128 + wn * 64;
#pragma unroll
  for (int mi = 0; mi < 4; ++mi) {
#pragma unroll
    for (int reg = 0; reg < 4; ++reg) {
      int r = wm * 64 + mi * 16 + ((lane >> 4) * 4) + reg;
      int rl = mt * 128 + r;
      if (rl < cnt) {
        size_t p = (size_t)(poff + rl);
        bf16* orow = gu_buf + p * (2 * I_DIM) + colb + (lane & 15);
#pragma unroll
        for (int ni = 0; ni < 4; ++ni)
          orow[ni * 16] = (bf16)acc[mi][ni][reg];
      }
    }
  }
}

// ---------------- silu * mul ----------------
__global__ __launch_bounds__(256) void silu_kernel(
    const bf16* __restrict__ gu, bf16* __restrict__ a)
{
  int idx = (blockIdx.x * 256 + threadIdx.x) * 4;  // over NPAIR * I_DIM
  int p = idx >> 10;
  int c = idx & 1023;
  const bf16* g = gu + (size_t)p * (2 * I_DIM) + c;
  bf16x4 g4 = *(const bf16x4*)(g);
  bf16x4 u4 = *(const bf16x4*)(g + I_DIM);
  bf16x4 r;
#pragma unroll
  for (int j = 0; j < 4; ++j) {
    float gf = (float)g4[j];
    float uf = (float)u4[j];
    float s = gf / (1.f + expf(-gf));
    r[j] = (bf16)(s * uf);
  }
  *(bf16x4*)(a + idx) = r;
}

// ---------------- down GEMM + scaled atomic scatter ----------------
__global__ __launch_bounds__(256) void down_kernel(
    const bf16* __restrict__ a_buf, const float* __restrict__ w_dn,
    const float* __restrict__ s_wdn,
    const int* __restrict__ off, const int* __restrict__ pair_token,
    const float* __restrict__ pair_scale, float* __restrict__ out)
{
  const int nt = blockIdx.x;   // 0..15 over N=H=2048
  const int mt = blockIdx.y;   // 0..7
  const int e  = blockIdx.z;   // 0..16
  const int poff = (e < 16) ? off[e]     : NPAIR_R;
  const int pend = (e < 16) ? off[e + 1] : NPAIR;
  const int cnt  = pend - poff;
  if (mt * 128 >= cnt) return;
  const float* __restrict__ B = (e < 16) ? (w_dn + (size_t)e * H_DIM * I_DIM) : s_wdn;

  __shared__ bf16 As[128 * LDSS];
  __shared__ bf16 Bs[128 * LDSS];

  const int tid = threadIdx.x;
  const int lane = tid & 63, wave = tid >> 6;
  const int wm = wave >> 1, wn = wave & 1;
  const int srow = tid >> 1;
  const int scol = (tid & 1) * 16;

  const bf16* __restrict__ Arow = a_buf + (size_t)(poff + mt * 128 + srow) * I_DIM;
  const float* __restrict__ Brow = B + (size_t)(nt * 128 + srow) * I_DIM;

  f32x4 acc[4][4];
  f32x4 zz = {0.f, 0.f, 0.f, 0.f};
#pragma unroll
  for (int mi = 0; mi < 4; ++mi)
#pragma unroll
    for (int ni = 0; ni < 4; ++ni) acc[mi][ni] = zz;

  for (int k0 = 0; k0 < I_DIM; k0 += 32) {
    bf16x8 a0 = *(const bf16x8*)(Arow + k0 + scol);
    bf16x8 a1 = *(const bf16x8*)(Arow + k0 + scol + 8);
    *(bf16x8*)(&As[srow * LDSS + scol])     = a0;
    *(bf16x8*)(&As[srow * LDSS + scol + 8]) = a1;
#pragma unroll
    for (int i = 0; i < 4; ++i) {
      float4 bv = *(const float4*)(Brow + k0 + scol + 4 * i);
      bf16x4 b4;
      b4[0] = (bf16)bv.x; b4[1] = (bf16)bv.y; b4[2] = (bf16)bv.z; b4[3] = (bf16)bv.w;
      *(bf16x4*)(&Bs[srow * LDSS + scol + 4 * i]) = b4;
    }
    __syncthreads();
    const int kq = (lane >> 4) * 8;
    bf16x8 af[4], bfv[4];
#pragma unroll
    for (int mi = 0; mi < 4; ++mi)
      af[mi] = *(const bf16x8*)(&As[(wm * 64 + mi * 16 + (lane & 15)) * LDSS + kq]);
#pragma unroll
    for (int ni = 0; ni < 4; ++ni)
      bfv[ni] = *(const bf16x8*)(&Bs[(wn * 64 + ni * 16 + (lane & 15)) * LDSS + kq]);
#pragma unroll
    for (int mi = 0; mi < 4; ++mi)
#pragma unroll
      for (int ni = 0; ni < 4; ++ni)
        acc[mi][ni] = __builtin_amdgcn_mfma_f32_16x16x32_bf16(af[mi], bfv[ni], acc[mi][ni], 0, 0, 0);
    __syncthreads();
  }

  const int colb = nt * 128 + wn * 64;
#pragma unroll
  for (int mi = 0; mi < 4; ++mi) {
#pragma unroll
    for (int reg = 0; reg < 4; ++reg) {
      int r = wm * 64 + mi * 16 + ((lane >> 4) * 4) + reg;
      int rl = mt * 128 + r;
      if (rl < cnt) {
        int p = poff + rl;
        int tok = pair_token[p];
        float sc = pair_scale[p];
        float* orow = out + (size_t)tok * H_DIM + colb + (lane & 15);
#pragma unroll
        for (int ni = 0; ni < 4; ++ni)
          atomicAdd(&orow[ni * 16], acc[mi][ni][reg] * sc);
      }
    }
  }
}

// ---------------- launch ----------------
extern "C" void kernel_launch(void* const* d_in, const int* in_sizes, int n_in,
                              void* d_out, int out_size, void* d_ws, size_t ws_size,
                              hipStream_t stream)
{
  const float* x     = (const float*)d_in[0];
  const float* gatew = (const float*)d_in[1];
  const float* ebias = (const float*)d_in[2];
  const float* w_gu  = (const float*)d_in[3];
  const float* w_dn  = (const float*)d_in[4];
  const float* s_wgu = (const float*)d_in[5];
  const float* s_wdn = (const float*)d_in[6];
  float* out = (float*)d_out;

  char* ws = (char*)d_ws;
  int*   off        = (int*)(ws + 0);        // 32 ints
  int*   counts     = (int*)(ws + 128);      // 16 ints
  int*   cursor     = (int*)(ws + 192);      // 16 ints
  int*   topk_ids   = (int*)(ws + 256);      // 4096 ints
  float* topk_w     = (float*)(ws + 16640);  // 4096 floats
  int*   pair_token = (int*)(ws + 33024);    // 5120 ints
  float* pair_scale = (float*)(ws + 53504);  // 5120 floats
  bf16*  gu_buf     = (bf16*)(ws + 73984);   // 5120*2048 bf16 = 20,971,520 B
  bf16*  a_buf      = (bf16*)(ws + 73984 + 20971520);  // 5120*1024 bf16 = 10,485,760 B

  hipMemsetAsync(out, 0, (size_t)T_TOK * H_DIM * sizeof(float), stream);
  hipMemsetAsync(ws + 128, 0, 128, stream);  // counts + cursor

  router_kernel<<<T_TOK, 256, 0, stream>>>(x, gatew, ebias, topk_ids, topk_w, counts);
  offsets_kernel<<<1, 64, 0, stream>>>(counts, off);
  scatter_kernel<<<NPAIR / 256, 256, 0, stream>>>(topk_ids, topk_w, off, cursor,
                                                  pair_token, pair_scale);
  dim3 g1(16, 8, 17);
  gateup_kernel<<<g1, 256, 0, stream>>>(x, w_gu, s_wgu, off, pair_token, gu_buf);
  silu_kernel<<<(NPAIR * I_DIM) / (256 * 4), 256, 0, stream>>>(gu_buf, a_buf);
  dim3 g2(16, 8, 17);
  down_kernel<<<g2, 256, 0, stream>>>(a_buf, w_dn, s_wdn, off, pair_token, pair_scale, out);
}